// Round 1
// 245.248 us; speedup vs baseline: 1.0016x; 1.0016x over previous
//
#include <hip/hip_runtime.h>
#include <math.h>

#define N_TOKENS    16384
#define MODEL_DIM   2048
#define NUM_EXPERTS 64
#define NK          (N_TOKENS * 2)          // 32768

// d_out layout (float32 elements)
#define OFF_TOKEN_ORDER 0
#define OFF_REVERSED    (NK)                // 32768
#define OFF_COMBINE     (2 * NK)            // 65536
#define OFF_SPLITS      (3 * NK)            // 98304
#define OFF_PROBS       (3 * NK + NUM_EXPERTS)

#define NSEG 256
#define NFRAG 16384            // 64 ksteps * 4 tiles * 64 lanes

typedef _Float16 half8 __attribute__((ext_vector_type(8)));
typedef float    f32x4 __attribute__((ext_vector_type(4)));

#define IMIN(a, b) ((a) < (b) ? (a) : (b))

// ---------------------------------------------------------------------------
// Kernel 1: pre-split W into f16 hi/lo MFMA fragments (W scaled x64 so hi is
// never f16-denormal; lo is the x4096-scaled exact residual). Also zeroes
// segHist for the gate kernel's atomics.
// Fragment fr = (kstep*4 + tile)*64 + lane holds 8 f16 of
// W[tile*16 + (lane&15)][kstep*32 + (lane>>4)*8 + 0..7].
// ---------------------------------------------------------------------------
__global__ __launch_bounds__(256) void preconvert(
    const float* __restrict__ w, half8* __restrict__ WH, half8* __restrict__ WL,
    int* __restrict__ segHist)
{
    const int fr = blockIdx.x * 256 + threadIdx.x;   // 0..16383
    const int lane = fr & 63;
    const int tile = (fr >> 6) & 3;
    const int kstep = fr >> 8;
    const int e = tile * 16 + (lane & 15);
    const int kb = kstep * 32 + (lane >> 4) * 8;
    const float* src = w + (size_t)e * MODEL_DIM + kb;
    const float4 w0 = *(const float4*)(src);
    const float4 w1 = *(const float4*)(src + 4);
    const float av[8] = {w0.x, w0.y, w0.z, w0.w, w1.x, w1.y, w1.z, w1.w};
    half8 hh, hl;
#pragma unroll
    for (int j = 0; j < 8; j++) {
        const float v = av[j] * 64.0f;
        const _Float16 h = (_Float16)v;
        hh[j] = h;
        hl[j] = (_Float16)((v - (float)h) * 4096.0f);
    }
    WH[fr] = hh;
    WL[fr] = hl;
    segHist[fr] = 0;        // NSEG*NUM_EXPERTS == 16384 exactly
}

// ---------------------------------------------------------------------------
// Kernel 2: fused gate. Grid 1024 blocks x 128 threads (2 waves).
// Each block: 16 tokens x 64 experts; waves split K (1024 each), fp64 fold
// every 256 K, cross-wave LDS reduce, then softmax/top2/combine/hist in the
// epilogue via 16-lane shuffles.
// f16 MFMA 16x16x32: A row=lane&15 (token), k=(lane>>4)*8+j;
//                    B col=lane&15 (expert), same k; C/D col=lane&15,
//                    row=(lane>>4)*4+reg.
// logit = (accH + accC/4096) / 64  (W was pre-scaled x64).
// ---------------------------------------------------------------------------

#define LOADB(BH_, BL_, G_) do {                                            \
    const size_t bb_ = (size_t)(G_) * 256 + lane;                           \
    _Pragma("unroll")                                                       \
    for (int t_ = 0; t_ < 4; t_++) {                                        \
        BH_[t_] = WH[bb_ + t_ * 64];                                        \
        BL_[t_] = WL[bb_ + t_ * 64];                                        \
    }                                                                       \
} while (0)

#define LOADA(DST_, KOFF_) do {                                             \
    const int ko_ = (KOFF_);                                                \
    _Pragma("unroll")                                                       \
    for (int s_ = 0; s_ < 4; s_++) {                                        \
        DST_[2*s_]   = *(const float4*)(px + ko_ + s_*32);                  \
        DST_[2*s_+1] = *(const float4*)(px + ko_ + s_*32 + 4);              \
    }                                                                       \
} while (0)

#define STEP(AV_, SI_, BHC_, BLC_, BHN_, BLN_, GN_) do {                    \
    LOADB(BHN_, BLN_, GN_);                                                 \
    const float4 A0_ = AV_[2*(SI_)];                                        \
    const float4 A1_ = AV_[2*(SI_)+1];                                      \
    const float av_[8] = {A0_.x,A0_.y,A0_.z,A0_.w,A1_.x,A1_.y,A1_.z,A1_.w}; \
    half8 ah_, al_;                                                         \
    _Pragma("unroll")                                                       \
    for (int j_ = 0; j_ < 8; j_++) {                                        \
        const float v_ = av_[j_];                                           \
        const _Float16 h_ = (_Float16)v_;                                   \
        ah_[j_] = h_;                                                       \
        al_[j_] = (_Float16)((v_ - (float)h_) * 4096.0f);                   \
    }                                                                       \
    _Pragma("unroll")                                                       \
    for (int t_ = 0; t_ < 4; t_++) {                                        \
        accH[t_] = __builtin_amdgcn_mfma_f32_16x16x32_f16(ah_, BHC_[t_], accH[t_], 0, 0, 0); \
        accC[t_] = __builtin_amdgcn_mfma_f32_16x16x32_f16(ah_, BLC_[t_], accC[t_], 0, 0, 0); \
        accC[t_] = __builtin_amdgcn_mfma_f32_16x16x32_f16(al_, BHC_[t_], accC[t_], 0, 0, 0); \
    }                                                                       \
} while (0)

__global__ __launch_bounds__(128, 2) void gate_fused(
    const float* __restrict__ x, const half8* __restrict__ WH,
    const half8* __restrict__ WL, float* __restrict__ out,
    int* __restrict__ flat_idx, int* __restrict__ segHist)
{
    __shared__ double lds_d[64 * 17];

    const int tid = threadIdx.x;
    const int wv = tid >> 6;          // 0,1 : K-halves
    const int lane = tid & 63;
    const int t0 = blockIdx.x * 16;
    const int col = lane & 15;
    const int kg = lane >> 4;

    const float* px = x + (size_t)(t0 + col) * MODEL_DIM + wv * 1024 + kg * 8;
    const int gbase = wv * 32;        // first B kstep for this wave

    f32x4 accH[4], accC[4];
    double accD[4][4];
#pragma unroll
    for (int t = 0; t < 4; t++) {
        accH[t] = (f32x4){0.f, 0.f, 0.f, 0.f};
        accC[t] = (f32x4){0.f, 0.f, 0.f, 0.f};
#pragma unroll
        for (int r = 0; r < 4; r++) accD[t][r] = 0.0;
    }

    float4 aA[8], aB[8];
    half8 bh0[4], bl0[4], bh1[4], bl1[4];

    LOADA(aA, 0);
    LOADB(bh0, bl0, gbase);

    for (int it = 0; it < 4; it++) {          // 4 iters x 8 ksteps x K=32
        const int ss = it * 2;
        const int gb = gbase + it * 8;
        LOADA(aB, (ss + 1) * 128);            // ss+1 <= 7 always
        STEP(aA, 0, bh0, bl0, bh1, bl1, IMIN(gb + 1, 63));
        STEP(aA, 1, bh1, bl1, bh0, bl0, IMIN(gb + 2, 63));
        STEP(aA, 2, bh0, bl0, bh1, bl1, IMIN(gb + 3, 63));
        STEP(aA, 3, bh1, bl1, bh0, bl0, IMIN(gb + 4, 63));
        LOADA(aA, IMIN(ss + 2, 7) * 128);
        STEP(aB, 0, bh0, bl0, bh1, bl1, IMIN(gb + 5, 63));
        STEP(aB, 1, bh1, bl1, bh0, bl0, IMIN(gb + 6, 63));
        STEP(aB, 2, bh0, bl0, bh1, bl1, IMIN(gb + 7, 63));
        STEP(aB, 3, bh1, bl1, bh0, bl0, IMIN(gb + 8, 63));
        // fp64 fold every 256 K
#pragma unroll
        for (int t = 0; t < 4; t++)
#pragma unroll
            for (int r = 0; r < 4; r++) {
                accD[t][r] += (double)accH[t][r] + (double)accC[t][r] * (1.0 / 4096.0);
                accH[t][r] = 0.0f;
                accC[t][r] = 0.0f;
            }
    }

    // cross-wave K reduce
    if (wv == 1) {
#pragma unroll
        for (int t = 0; t < 4; t++)
#pragma unroll
            for (int r = 0; r < 4; r++)
                lds_d[lane * 17 + t * 4 + r] = accD[t][r];
    }
    __syncthreads();
    if (wv == 1) return;

#pragma unroll
    for (int t = 0; t < 4; t++)
#pragma unroll
        for (int r = 0; r < 4; r++)
            accD[t][r] += lds_d[lane * 17 + t * 4 + r];

    // ---- epilogue: per token row, softmax + top2 + combine + hist ----
    const int rowg = lane >> 4;
#pragma unroll
    for (int r = 0; r < 4; r++) {
        float lv[4];
#pragma unroll
        for (int t = 0; t < 4; t++) lv[t] = (float)(accD[t][r] * (1.0 / 64.0));

        float m = fmaxf(fmaxf(lv[0], lv[1]), fmaxf(lv[2], lv[3]));
#pragma unroll
        for (int d = 1; d < 16; d <<= 1) m = fmaxf(m, __shfl_xor(m, d));

        // local top2 over this lane's 4 experts (ascending index)
        float l1 = -INFINITY, l2 = -INFINITY;
        int i1 = 0, i2 = 0;
#pragma unroll
        for (int t = 0; t < 4; t++) {
            const float l = lv[t];
            const int e = t * 16 + col;
            if (l > l1)      { l2 = l1; i2 = i1; l1 = l; i1 = e; }
            else if (l > l2) { l2 = l;  i2 = e; }
        }
        // cross-lane top2 merge within the 16-lane row group (lowest-idx ties)
#pragma unroll
        for (int d = 1; d < 16; d <<= 1) {
            const float ol1 = __shfl_xor(l1, d), ol2 = __shfl_xor(l2, d);
            const int   oi1 = __shfl_xor(i1, d), oi2 = __shfl_xor(i2, d);
            if (ol1 > l1 || (ol1 == l1 && oi1 < i1)) {
                if (l1 > ol2 || (l1 == ol2 && i1 < oi2)) { l2 = l1;  i2 = i1;  }
                else                                     { l2 = ol2; i2 = oi2; }
                l1 = ol1; i1 = oi1;
            } else if (ol1 > l2 || (ol1 == l2 && oi1 < i2)) {
                l2 = ol1; i2 = oi1;
            }
        }

        float ex[4];
        double sd = 0.0;
#pragma unroll
        for (int t = 0; t < 4; t++) { ex[t] = expf(lv[t] - m); sd += (double)ex[t]; }
#pragma unroll
        for (int d = 1; d < 16; d <<= 1) sd += __shfl_xor(sd, d);
        const float inv = (float)(1.0 / sd);

        const int tok = t0 + rowg * 4 + r;
        float* pp = out + OFF_PROBS + (size_t)tok * NUM_EXPERTS + col;
#pragma unroll
        for (int t = 0; t < 4; t++) pp[t * 16] = ex[t] * inv;

        if (col == 0) {
            const float p1 = expf(l1 - m) * inv;
            const float p2 = expf(l2 - m) * inv;
            const float e2 = expf(p2 - p1);
            const float rr = 1.0f / (1.0f + e2);
            out[OFF_COMBINE + 2 * tok]     = rr;
            out[OFF_COMBINE + 2 * tok + 1] = e2 * rr;
            flat_idx[2 * tok]     = i1;
            flat_idx[2 * tok + 1] = i2;
            atomicAdd(&segHist[(tok >> 6) * NUM_EXPERTS + i1], 1);
            atomicAdd(&segHist[(tok >> 6) * NUM_EXPERTS + i2], 1);
        }
    }
}

// ---------------------------------------------------------------------------
// Kernel 3: scan segment hists. 2-level: 4 groups of 64 segments (chain len 64)
// + wave-shuffle prefix for expert bases. 1 block x 256 threads. (unchanged)
// ---------------------------------------------------------------------------
__global__ __launch_bounds__(256) void scan_kernel(
    const int* __restrict__ segHist, int* __restrict__ segOff,
    float* __restrict__ out)
{
    __shared__ int h[NSEG * NUM_EXPERTS];   // 64 KB
    __shared__ int gtot[4 * NUM_EXPERTS];
    __shared__ int base[NUM_EXPERTS];
    const int tid = threadIdx.x;
    for (int i = tid; i < NSEG * NUM_EXPERTS / 4; i += 256)
        *(int4*)(h + i * 4) = *(const int4*)(segHist + i * 4);
    __syncthreads();

    const int e = tid & 63;
    const int g = tid >> 6;                 // 0..3
    int run = 0;
    for (int s = g * 64; s < g * 64 + 64; s++) {
        const int idx = s * NUM_EXPERTS + e;
        const int v = h[idx];
        h[idx] = run;
        run += v;
    }
    gtot[g * NUM_EXPERTS + e] = run;
    __syncthreads();

    if (tid < NUM_EXPERTS) {
        int b = 0;
#pragma unroll
        for (int gg = 0; gg < 4; gg++) {
            const int t = gtot[gg * NUM_EXPERTS + tid];
            gtot[gg * NUM_EXPERTS + tid] = b;
            b += t;
        }
        out[OFF_SPLITS + tid] = (float)b;
        int xs = b;                          // inclusive wave scan over experts
#pragma unroll
        for (int off = 1; off < 64; off <<= 1) {
            const int v = __shfl_up(xs, off);
            if (tid >= off) xs += v;
        }
        base[tid] = xs - b;                  // exclusive
    }
    __syncthreads();

    const int myoff = gtot[g * NUM_EXPERTS + e] + base[e];
    for (int s = g * 64; s < g * 64 + 64; s++) {
        const int idx = s * NUM_EXPERTS + e;
        segOff[idx] = h[idx] + myoff;
    }
}

// ---------------------------------------------------------------------------
// Kernel 4: stable scatter via ballot-match ranks (unchanged, verified)
// ---------------------------------------------------------------------------
__global__ __launch_bounds__(256) void scatter_kernel(
    const int* __restrict__ flat_idx, const int* __restrict__ segOff,
    float* __restrict__ out)
{
    __shared__ int cnt[2 * NUM_EXPERTS];
    const int tid = threadIdx.x;
    const int i = blockIdx.x * 256 + tid;
    const int e = flat_idx[i];
    const int lane = tid & 63;
    const int wv = tid >> 6;
    const int segslot = wv >> 1;
    const int seg = i >> 7;

    if (tid < 2 * NUM_EXPERTS) cnt[tid] = 0;
    __syncthreads();

    unsigned long long match = ~0ull;
#pragma unroll
    for (int b = 0; b < 6; b++) {
        const unsigned long long m = __ballot((e >> b) & 1);
        match &= ((e >> b) & 1) ? m : ~m;
    }
    const int rank = __popcll(match & ((1ull << lane) - 1ull));

    int pos = 0;
    if ((wv & 1) == 0) {
        pos = segOff[seg * NUM_EXPERTS + e] + rank;
        if (lane == __builtin_ctzll(match))
            cnt[segslot * NUM_EXPERTS + e] = __popcll(match);
    }
    __syncthreads();
    if ((wv & 1) == 1)
        pos = segOff[seg * NUM_EXPERTS + e] + cnt[segslot * NUM_EXPERTS + e] + rank;

    out[OFF_TOKEN_ORDER + pos] = (float)(i >> 1);
    out[OFF_REVERSED + i]      = (float)pos;
}

// ---------------------------------------------------------------------------
extern "C" void kernel_launch(void* const* d_in, const int* in_sizes, int n_in,
                              void* d_out, int out_size, void* d_ws, size_t ws_size,
                              hipStream_t stream) {
    const float* x = (const float*)d_in[0];   // [16384, 2048] fp32
    const float* w = (const float*)d_in[1];   // [64, 2048] fp32
    float* out = (float*)d_out;

    int* flat_idx = (int*)d_ws;                          // NK ints
    int* segHist  = flat_idx + NK;                       // 256*64
    int* segOff   = segHist + NSEG * NUM_EXPERTS;        // 256*64
    half8* WH = (half8*)(segOff + NSEG * NUM_EXPERTS);   // 16384 frags (256 KB)
    half8* WL = WH + NFRAG;                              // 256 KB

    preconvert<<<64, 256, 0, stream>>>(w, WH, WL, segHist);
    gate_fused<<<N_TOKENS / 16, 128, 0, stream>>>(x, WH, WL, out, flat_idx, segHist);
    scan_kernel<<<1, 256, 0, stream>>>(segHist, segOff, out);
    scatter_kernel<<<NK / 256, 256, 0, stream>>>(flat_idx, segOff, out);
}

// Round 2
// 224.838 us; speedup vs baseline: 1.0925x; 1.0908x over previous
//
#include <hip/hip_runtime.h>
#include <math.h>

#define N_TOKENS    16384
#define MODEL_DIM   2048
#define NUM_EXPERTS 64
#define NK          (N_TOKENS * 2)          // 32768

// d_out layout (float32 elements)
#define OFF_TOKEN_ORDER 0
#define OFF_REVERSED    (NK)                // 32768
#define OFF_COMBINE     (2 * NK)            // 65536
#define OFF_SPLITS      (3 * NK)            // 98304
#define OFF_PROBS       (3 * NK + NUM_EXPERTS)

#define NSEG 256
#define NFRAG 16384            // 64 ksteps * 4 tiles * 64 lanes

// staging geometry (per kstep): B = 2 kh * 4 tiles * 2 (H,L) * 1KB = 16KB
//                               A = 2 kh * 2 tg * 2 cc * 1KB        = 8KB
#define B_BYTES  16384
#define A_BYTES  8192
#define STAGE_BYTES (B_BYTES + A_BYTES)     // 24KB, double-buffered -> 48KB

typedef _Float16 half8 __attribute__((ext_vector_type(8)));
typedef float    f32x4 __attribute__((ext_vector_type(4)));

#define MEMFENCE asm volatile("" ::: "memory")

__device__ __forceinline__ void glds16(const void* g, void* l) {
    __builtin_amdgcn_global_load_lds(
        (const __attribute__((address_space(1))) void*)g,
        (__attribute__((address_space(3))) void*)l, 16, 0, 0);
}

// ---------------------------------------------------------------------------
// Kernel 1: pre-split W into f16 hi/lo MFMA fragments (W scaled x64 so hi is
// never f16-denormal; lo is the x4096-scaled exact residual). Also zeroes
// segHist. Fragment fr = (kstep*4 + tile)*64 + lane holds 8 f16 of
// W[tile*16 + (lane&15)][kstep*32 + (lane>>4)*8 + 0..7].
// ---------------------------------------------------------------------------
__global__ __launch_bounds__(256) void preconvert(
    const float* __restrict__ w, half8* __restrict__ WH, half8* __restrict__ WL,
    int* __restrict__ segHist)
{
    const int fr = blockIdx.x * 256 + threadIdx.x;   // 0..16383
    const int lane = fr & 63;
    const int tile = (fr >> 6) & 3;
    const int kstep = fr >> 8;
    const int e = tile * 16 + (lane & 15);
    const int kb = kstep * 32 + (lane >> 4) * 8;
    const float* src = w + (size_t)e * MODEL_DIM + kb;
    const float4 w0 = *(const float4*)(src);
    const float4 w1 = *(const float4*)(src + 4);
    const float av[8] = {w0.x, w0.y, w0.z, w0.w, w1.x, w1.y, w1.z, w1.w};
    half8 hh, hl;
#pragma unroll
    for (int j = 0; j < 8; j++) {
        const float v = av[j] * 64.0f;
        const _Float16 h = (_Float16)v;
        hh[j] = h;
        hl[j] = (_Float16)((v - (float)h) * 4096.0f);
    }
    WH[fr] = hh;
    WL[fr] = hl;
    segHist[fr] = 0;        // NSEG*NUM_EXPERTS == 16384 exactly
}

// ---------------------------------------------------------------------------
// Kernel 2: fused gate, fully LDS-staged via global_load_lds.
// Grid 512 blocks x 256 threads (4 waves = 2 token-groups x 2 K-halves).
// Block: 32 tokens x 64 experts. Per kstep (K=32): stage 24KB (B 16KB + A 8KB)
// into the next buffer with 6 global_load_lds per wave, counted vmcnt(6)
// (never drained in-loop), raw s_barrier x2. fp64 fold every 8 ksteps (256 K),
// cross-K-half fp64 reduce through (aliased) LDS, then softmax/top2/combine/
// hist epilogue per 16-lane row group. Numerics identical to the passing
// round-1 kernel: logit = (accH + accC/4096)/64, W pre-scaled x64.
// ---------------------------------------------------------------------------
__global__ __launch_bounds__(256, 2) void gate_fused(
    const float* __restrict__ x, const half8* __restrict__ WH,
    const half8* __restrict__ WL, float* __restrict__ out,
    int* __restrict__ flat_idx, int* __restrict__ segHist)
{
    __shared__ alignas(16) unsigned char smem[2 * STAGE_BYTES];   // 48KB

    const int tid  = threadIdx.x;
    const int wv   = tid >> 6;          // 0..3
    const int lane = tid & 63;
    const int kh   = wv & 1;            // K-half
    const int tg   = wv >> 1;           // token-group
    const int t0   = blockIdx.x * 32;
    const int col  = lane & 15;
    const int kg   = lane >> 4;

    // ---- per-wave staging descriptors (6 chunks of 1KB per kstep) ----
    const unsigned char* s_ptr[6];
    int s_stride[6];
    int s_off[6];
#pragma unroll
    for (int i = 0; i < 6; i++) {
        const int c = wv * 6 + i;       // 0..23: 0-15 = B, 16-23 = A
        if (c < 16) {
            const int hl   = c & 1;
            const int tile = (c >> 1) & 3;
            const int ckh  = c >> 3;
            const half8* base = (hl ? WL : WH) + ((size_t)((ckh * 32) * 4 + tile) * 64 + lane);
            s_ptr[i]    = (const unsigned char*)base;
            s_stride[i] = 4096;                      // +4 frags per kstep
            s_off[i]    = c * 1024 + lane * 16;
        } else {
            const int a   = c - 16;                  // a = ckh*4 + ctg*2 + cc
            const int cc  = a & 1;
            const int ctg = (a >> 1) & 1;
            const int ckh = a >> 2;
            const float* base = x + (size_t)(t0 + ctg * 16 + (lane & 15)) * MODEL_DIM
                              + ckh * 1024 + (lane >> 4) * 8 + cc * 4;
            s_ptr[i]    = (const unsigned char*)base;
            s_stride[i] = 128;                       // +32 floats per kstep
            s_off[i]    = B_BYTES + a * 1024 + lane * 16;
        }
    }

    f32x4 accH[4], accC[4];
    double accD[4][4];
#pragma unroll
    for (int t = 0; t < 4; t++) {
        accH[t] = (f32x4){0.f, 0.f, 0.f, 0.f};
        accC[t] = (f32x4){0.f, 0.f, 0.f, 0.f};
#pragma unroll
        for (int r = 0; r < 4; r++) accD[t][r] = 0.0;
    }

    // prologue: stage kstep 0 into buf0
#pragma unroll
    for (int i = 0; i < 6; i++) glds16(s_ptr[i], smem + s_off[i]);

    const int aoff = B_BYTES + (kh * 4 + tg * 2) * 1024 + lane * 16;
    const int boff = (kh * 4) * 2048 + lane * 16;

    for (int j = 0; j < 32; j++) {
        // stage kstep j+1 into the other buffer (tail restages j=31: harmless)
        const int jn = (j < 31) ? j + 1 : 31;
        unsigned char* nbuf = smem + ((j + 1) & 1) * STAGE_BYTES;
#pragma unroll
        for (int i = 0; i < 6; i++)
            glds16(s_ptr[i] + (size_t)jn * s_stride[i], nbuf + s_off[i]);

        asm volatile("s_waitcnt vmcnt(6)" ::: "memory");   // my kstep-j stores landed
        __builtin_amdgcn_s_barrier();                      // everyone's landed
        MEMFENCE;

        const unsigned char* buf = smem + (j & 1) * STAGE_BYTES;

        // A fragment: 8 floats -> f16 hi/lo split
        const float4 a0 = *(const float4*)(buf + aoff);
        const float4 a1 = *(const float4*)(buf + aoff + 1024);
        const float av[8] = {a0.x, a0.y, a0.z, a0.w, a1.x, a1.y, a1.z, a1.w};
        half8 ah, al;
#pragma unroll
        for (int q = 0; q < 8; q++) {
            const float v = av[q];
            const _Float16 h = (_Float16)v;
            ah[q] = h;
            al[q] = (_Float16)((v - (float)h) * 4096.0f);
        }

#pragma unroll
        for (int t = 0; t < 4; t++) {
            const half8 bh = *(const half8*)(buf + boff + t * 2048);
            const half8 bl = *(const half8*)(buf + boff + t * 2048 + 1024);
            accH[t] = __builtin_amdgcn_mfma_f32_16x16x32_f16(ah, bh, accH[t], 0, 0, 0);
            accC[t] = __builtin_amdgcn_mfma_f32_16x16x32_f16(ah, bl, accC[t], 0, 0, 0);
            accC[t] = __builtin_amdgcn_mfma_f32_16x16x32_f16(al, bh, accC[t], 0, 0, 0);
        }

        if ((j & 7) == 7) {     // fp64 fold every 256 K
#pragma unroll
            for (int t = 0; t < 4; t++)
#pragma unroll
                for (int r = 0; r < 4; r++) {
                    accD[t][r] += (double)accH[t][r] + (double)accC[t][r] * (1.0 / 4096.0);
                    accH[t][r] = 0.0f;
                    accC[t][r] = 0.0f;
                }
        }

        MEMFENCE;
        __builtin_amdgcn_s_barrier();   // all reads of buf done before restaging it
    }

    // drain tail staging before aliasing LDS for the fp64 reduce
    asm volatile("s_waitcnt vmcnt(0)" ::: "memory");
    __syncthreads();

    double* red = (double*)smem;        // 2*64*17 doubles = 17KB, aliases buf0
    if (kh == 1) {
#pragma unroll
        for (int t = 0; t < 4; t++)
#pragma unroll
            for (int r = 0; r < 4; r++)
                red[(tg * 64 + lane) * 17 + t * 4 + r] = accD[t][r];
    }
    __syncthreads();
    if (kh == 1) return;

#pragma unroll
    for (int t = 0; t < 4; t++)
#pragma unroll
        for (int r = 0; r < 4; r++)
            accD[t][r] += red[(tg * 64 + lane) * 17 + t * 4 + r];

    // ---- epilogue: per token row, softmax + top2 + combine + hist ----
    const int rowg = lane >> 4;
#pragma unroll
    for (int r = 0; r < 4; r++) {
        float lv[4];
#pragma unroll
        for (int t = 0; t < 4; t++) lv[t] = (float)(accD[t][r] * (1.0 / 64.0));

        float m = fmaxf(fmaxf(lv[0], lv[1]), fmaxf(lv[2], lv[3]));
#pragma unroll
        for (int d = 1; d < 16; d <<= 1) m = fmaxf(m, __shfl_xor(m, d));

        // local top2 over this lane's 4 experts (ascending index)
        float l1 = -INFINITY, l2 = -INFINITY;
        int i1 = 0, i2 = 0;
#pragma unroll
        for (int t = 0; t < 4; t++) {
            const float l = lv[t];
            const int e = t * 16 + col;
            if (l > l1)      { l2 = l1; i2 = i1; l1 = l; i1 = e; }
            else if (l > l2) { l2 = l;  i2 = e; }
        }
        // cross-lane top2 merge within the 16-lane row group (lowest-idx ties)
#pragma unroll
        for (int d = 1; d < 16; d <<= 1) {
            const float ol1 = __shfl_xor(l1, d), ol2 = __shfl_xor(l2, d);
            const int   oi1 = __shfl_xor(i1, d), oi2 = __shfl_xor(i2, d);
            if (ol1 > l1 || (ol1 == l1 && oi1 < i1)) {
                if (l1 > ol2 || (l1 == ol2 && i1 < oi2)) { l2 = l1;  i2 = i1;  }
                else                                     { l2 = ol2; i2 = oi2; }
                l1 = ol1; i1 = oi1;
            } else if (ol1 > l2 || (ol1 == l2 && oi1 < i2)) {
                l2 = ol1; i2 = oi1;
            }
        }

        float ex[4];
        double sd = 0.0;
#pragma unroll
        for (int t = 0; t < 4; t++) { ex[t] = expf(lv[t] - m); sd += (double)ex[t]; }
#pragma unroll
        for (int d = 1; d < 16; d <<= 1) sd += __shfl_xor(sd, d);
        const float inv = (float)(1.0 / sd);

        const int tok = t0 + tg * 16 + rowg * 4 + r;
        float* pp = out + OFF_PROBS + (size_t)tok * NUM_EXPERTS + col;
#pragma unroll
        for (int t = 0; t < 4; t++) pp[t * 16] = ex[t] * inv;

        if (col == 0) {
            const float p1 = expf(l1 - m) * inv;
            const float p2 = expf(l2 - m) * inv;
            const float e2 = expf(p2 - p1);
            const float rr = 1.0f / (1.0f + e2);
            out[OFF_COMBINE + 2 * tok]     = rr;
            out[OFF_COMBINE + 2 * tok + 1] = e2 * rr;
            flat_idx[2 * tok]     = i1;
            flat_idx[2 * tok + 1] = i2;
            atomicAdd(&segHist[(tok >> 6) * NUM_EXPERTS + i1], 1);
            atomicAdd(&segHist[(tok >> 6) * NUM_EXPERTS + i2], 1);
        }
    }
}

// ---------------------------------------------------------------------------
// Kernel 3: scan segment hists. 2-level: 4 groups of 64 segments (chain len 64)
// + wave-shuffle prefix for expert bases. 1 block x 256 threads. (unchanged)
// ---------------------------------------------------------------------------
__global__ __launch_bounds__(256) void scan_kernel(
    const int* __restrict__ segHist, int* __restrict__ segOff,
    float* __restrict__ out)
{
    __shared__ int h[NSEG * NUM_EXPERTS];   // 64 KB
    __shared__ int gtot[4 * NUM_EXPERTS];
    __shared__ int base[NUM_EXPERTS];
    const int tid = threadIdx.x;
    for (int i = tid; i < NSEG * NUM_EXPERTS / 4; i += 256)
        *(int4*)(h + i * 4) = *(const int4*)(segHist + i * 4);
    __syncthreads();

    const int e = tid & 63;
    const int g = tid >> 6;                 // 0..3
    int run = 0;
    for (int s = g * 64; s < g * 64 + 64; s++) {
        const int idx = s * NUM_EXPERTS + e;
        const int v = h[idx];
        h[idx] = run;
        run += v;
    }
    gtot[g * NUM_EXPERTS + e] = run;
    __syncthreads();

    if (tid < NUM_EXPERTS) {
        int b = 0;
#pragma unroll
        for (int gg = 0; gg < 4; gg++) {
            const int t = gtot[gg * NUM_EXPERTS + tid];
            gtot[gg * NUM_EXPERTS + tid] = b;
            b += t;
        }
        out[OFF_SPLITS + tid] = (float)b;
        int xs = b;                          // inclusive wave scan over experts
#pragma unroll
        for (int off = 1; off < 64; off <<= 1) {
            const int v = __shfl_up(xs, off);
            if (tid >= off) xs += v;
        }
        base[tid] = xs - b;                  // exclusive
    }
    __syncthreads();

    const int myoff = gtot[g * NUM_EXPERTS + e] + base[e];
    for (int s = g * 64; s < g * 64 + 64; s++) {
        const int idx = s * NUM_EXPERTS + e;
        segOff[idx] = h[idx] + myoff;
    }
}

// ---------------------------------------------------------------------------
// Kernel 4: stable scatter via ballot-match ranks (unchanged, verified)
// ---------------------------------------------------------------------------
__global__ __launch_bounds__(256) void scatter_kernel(
    const int* __restrict__ flat_idx, const int* __restrict__ segOff,
    float* __restrict__ out)
{
    __shared__ int cnt[2 * NUM_EXPERTS];
    const int tid = threadIdx.x;
    const int i = blockIdx.x * 256 + tid;
    const int e = flat_idx[i];
    const int lane = tid & 63;
    const int wv = tid >> 6;
    const int segslot = wv >> 1;
    const int seg = i >> 7;

    if (tid < 2 * NUM_EXPERTS) cnt[tid] = 0;
    __syncthreads();

    unsigned long long match = ~0ull;
#pragma unroll
    for (int b = 0; b < 6; b++) {
        const unsigned long long m = __ballot((e >> b) & 1);
        match &= ((e >> b) & 1) ? m : ~m;
    }
    const int rank = __popcll(match & ((1ull << lane) - 1ull));

    int pos = 0;
    if ((wv & 1) == 0) {
        pos = segOff[seg * NUM_EXPERTS + e] + rank;
        if (lane == __builtin_ctzll(match))
            cnt[segslot * NUM_EXPERTS + e] = __popcll(match);
    }
    __syncthreads();
    if ((wv & 1) == 1)
        pos = segOff[seg * NUM_EXPERTS + e] + cnt[segslot * NUM_EXPERTS + e] + rank;

    out[OFF_TOKEN_ORDER + pos] = (float)(i >> 1);
    out[OFF_REVERSED + i]      = (float)pos;
}

// ---------------------------------------------------------------------------
extern "C" void kernel_launch(void* const* d_in, const int* in_sizes, int n_in,
                              void* d_out, int out_size, void* d_ws, size_t ws_size,
                              hipStream_t stream) {
    const float* x = (const float*)d_in[0];   // [16384, 2048] fp32
    const float* w = (const float*)d_in[1];   // [64, 2048] fp32
    float* out = (float*)d_out;

    int* flat_idx = (int*)d_ws;                          // NK ints
    int* segHist  = flat_idx + NK;                       // 256*64
    int* segOff   = segHist + NSEG * NUM_EXPERTS;        // 256*64
    half8* WH = (half8*)(segOff + NSEG * NUM_EXPERTS);   // 16384 frags (256 KB)
    half8* WL = WH + NFRAG;                              // 256 KB

    preconvert<<<64, 256, 0, stream>>>(w, WH, WL, segHist);
    gate_fused<<<512, 256, 0, stream>>>(x, WH, WL, out, flat_idx, segHist);
    scan_kernel<<<1, 256, 0, stream>>>(segHist, segOff, out);
    scatter_kernel<<<NK / 256, 256, 0, stream>>>(flat_idx, segOff, out);
}

// Round 3
// 224.219 us; speedup vs baseline: 1.0955x; 1.0028x over previous
//
#include <hip/hip_runtime.h>
#include <math.h>

#define N_TOKENS    16384
#define MODEL_DIM   2048
#define NUM_EXPERTS 64
#define NK          (N_TOKENS * 2)          // 32768

// d_out layout (float32 elements)
#define OFF_TOKEN_ORDER 0
#define OFF_REVERSED    (NK)                // 32768
#define OFF_COMBINE     (2 * NK)            // 65536
#define OFF_SPLITS      (3 * NK)            // 98304
#define OFF_PROBS       (3 * NK + NUM_EXPERTS)

#define NSEG 256
#define NFRAG 16384            // 64 ksteps * 4 tiles * 64 lanes

// staging geometry (per kstep): B = 2 kh * 4 tiles * 2 (H,L) * 1KB = 16KB
//                               A = 2 kh * 4 tokgrp * 1KB           = 8KB
#define B_BYTES  16384
#define A_BYTES  8192
#define STAGE_BYTES (B_BYTES + A_BYTES)     // 24KB, triple-buffered -> 72KB

typedef _Float16 half8 __attribute__((ext_vector_type(8)));
typedef float    f32x4 __attribute__((ext_vector_type(4)));

#define MEMFENCE asm volatile("" ::: "memory")

__device__ __forceinline__ void glds16(const void* g, void* l) {
    __builtin_amdgcn_global_load_lds(
        (const __attribute__((address_space(1))) void*)g,
        (__attribute__((address_space(3))) void*)l, 16, 0, 0);
}

// ---------------------------------------------------------------------------
// Kernel 1: pre-split W into f16 hi/lo MFMA fragments (W scaled x64 so hi is
// never f16-denormal; lo is the x4096-scaled exact residual). Also zeroes
// segHist. Fragment fr = (kstep*4 + tile)*64 + lane holds 8 f16 of
// W[tile*16 + (lane&15)][kstep*32 + (lane>>4)*8 + 0..7].
// ---------------------------------------------------------------------------
__global__ __launch_bounds__(256) void preconvert(
    const float* __restrict__ w, half8* __restrict__ WH, half8* __restrict__ WL,
    int* __restrict__ segHist)
{
    const int fr = blockIdx.x * 256 + threadIdx.x;   // 0..16383
    const int lane = fr & 63;
    const int tile = (fr >> 6) & 3;
    const int kstep = fr >> 8;
    const int e = tile * 16 + (lane & 15);
    const int kb = kstep * 32 + (lane >> 4) * 8;
    const float* src = w + (size_t)e * MODEL_DIM + kb;
    const float4 w0 = *(const float4*)(src);
    const float4 w1 = *(const float4*)(src + 4);
    const float av[8] = {w0.x, w0.y, w0.z, w0.w, w1.x, w1.y, w1.z, w1.w};
    half8 hh, hl;
#pragma unroll
    for (int j = 0; j < 8; j++) {
        const float v = av[j] * 64.0f;
        const _Float16 h = (_Float16)v;
        hh[j] = h;
        hl[j] = (_Float16)((v - (float)h) * 4096.0f);
    }
    WH[fr] = hh;
    WL[fr] = hl;
    segHist[fr] = 0;        // NSEG*NUM_EXPERTS == 16384 exactly
}

// ---------------------------------------------------------------------------
// Kernel 2: fused gate, fully LDS-staged via coalesced global_load_lds.
// Grid 512 blocks x 256 threads (4 waves = 2 token-groups x 2 K-halves).
// Block: 32 tokens x 64 experts. Per kstep (K=32): stage 24KB as 24 fully
// contiguous 1KB streams, dealt round-robin (c = i*4 + wv) so each wave issues
// 4 B-streams + 2 A-streams. A rows are packed 8 lanes/row (128B contiguous)
// with the 16B piece index XOR-permuted by (row&7) at the GLOBAL address
// (inverse-swizzled source + linear LDS dest + swizzled ds_read), making the
// A ds_read_b128 bank-minimal. Triple-buffered, counted vmcnt(12) (2 ksteps
// in flight, never drained in-loop), raw s_barrier x2 per kstep.
// fp64 fold every 8 ksteps (256 K), cross-K-half fp64 reduce through aliased
// LDS, then softmax/top2/combine/hist epilogue per 16-lane row group.
// Numerics identical to the passing round-2 kernel:
// logit = (accH + accC/4096)/64, W pre-scaled x64.
// ---------------------------------------------------------------------------
__global__ __launch_bounds__(256, 2) void gate_fused(
    const float* __restrict__ x, const half8* __restrict__ WH,
    const half8* __restrict__ WL, float* __restrict__ out,
    int* __restrict__ flat_idx, int* __restrict__ segHist)
{
    __shared__ alignas(16) unsigned char smem[3 * STAGE_BYTES];   // 72KB

    const int tid  = threadIdx.x;
    const int wv   = tid >> 6;          // 0..3
    const int lane = tid & 63;
    const int kh   = wv & 1;            // K-half
    const int tg   = wv >> 1;           // token-group
    const int t0   = blockIdx.x * 32;
    const int col  = lane & 15;
    const int kg   = lane >> 4;

    // ---- per-wave staging descriptors (6 contiguous-1KB streams per kstep) --
    const unsigned char* s_ptr[6];
    int s_stride[6];
    int s_off[6];
#pragma unroll
    for (int i = 0; i < 6; i++) {
        const int c = i * 4 + wv;       // 0..23: 0-15 = B, 16-23 = A
        if (c < 16) {
            const int hl   = c & 1;
            const int tile = (c >> 1) & 3;
            const int ckh  = c >> 3;
            const half8* base = (hl ? WL : WH) + ((size_t)(ckh * 32 * 4 + tile) * 64 + lane);
            s_ptr[i]    = (const unsigned char*)base;
            s_stride[i] = 4096;                      // +4 frags per kstep
            s_off[i]    = c * 1024 + lane * 16;
        } else {
            // A: 8 lanes per token row (128B contiguous), piece XOR-permuted
            const int a   = c - 16;                  // a = ckh*4 + tgp
            const int ckh = a >> 2;
            const int tgp = a & 3;
            const int tok = t0 + tgp * 8 + (lane >> 3);
            const int p   = (lane & 7) ^ (lane >> 3);          // inverse swizzle
            s_ptr[i]    = (const unsigned char*)(x + (size_t)tok * MODEL_DIM
                                                 + ckh * 1024 + p * 4);
            s_stride[i] = 128;                       // +32 floats per kstep
            s_off[i]    = B_BYTES + a * 1024 + lane * 16;
        }
    }

    f32x4 accH[4], accC[4];
    double accD[4][4];
#pragma unroll
    for (int t = 0; t < 4; t++) {
        accH[t] = (f32x4){0.f, 0.f, 0.f, 0.f};
        accC[t] = (f32x4){0.f, 0.f, 0.f, 0.f};
#pragma unroll
        for (int r = 0; r < 4; r++) accD[t][r] = 0.0;
    }

    // prologue: stage kstep 0 -> buf0, kstep 1 -> buf1
#pragma unroll
    for (int i = 0; i < 6; i++) glds16(s_ptr[i], smem + s_off[i]);
#pragma unroll
    for (int i = 0; i < 6; i++)
        glds16(s_ptr[i] + s_stride[i], smem + STAGE_BYTES + s_off[i]);

    // reader offsets (swizzled A read: piece p at slot p^(row&7))
    const int a_r   = kh * 4 + tg * 2 + (col >> 3);
    const int tl    = col & 7;
    const int abase = B_BYTES + a_r * 1024 + tl * 128;
    const int aoff0 = abase + (((kg * 2) ^ tl) << 4);
    const int aoff1 = abase + (((kg * 2 + 1) ^ tl) << 4);
    const int boff  = kh * 8192 + lane * 16;

    int cur = 0;        // j % 3
    int nxt = 2;        // (j+2) % 3

    for (int j = 0; j < 32; j++) {
        // stage kstep j+2 two buffers ahead (tail restages 31: never read)
        const int jn = (j < 30) ? j + 2 : 31;
        unsigned char* nbuf = smem + nxt * STAGE_BYTES;
#pragma unroll
        for (int i = 0; i < 6; i++)
            glds16(s_ptr[i] + (size_t)jn * s_stride[i], nbuf + s_off[i]);

        asm volatile("s_waitcnt vmcnt(12)" ::: "memory");  // my kstep-j stores landed
        __builtin_amdgcn_s_barrier();                      // everyone's landed
        MEMFENCE;

        const unsigned char* buf = smem + cur * STAGE_BYTES;

        // A fragment: 8 floats -> f16 hi/lo split
        const float4 a0 = *(const float4*)(buf + aoff0);
        const float4 a1 = *(const float4*)(buf + aoff1);
        const float av[8] = {a0.x, a0.y, a0.z, a0.w, a1.x, a1.y, a1.z, a1.w};
        half8 ah, al;
#pragma unroll
        for (int q = 0; q < 8; q++) {
            const float v = av[q];
            const _Float16 h = (_Float16)v;
            ah[q] = h;
            al[q] = (_Float16)((v - (float)h) * 4096.0f);
        }

#pragma unroll
        for (int t = 0; t < 4; t++) {
            const half8 bh = *(const half8*)(buf + boff + t * 2048);
            const half8 bl = *(const half8*)(buf + boff + t * 2048 + 1024);
            accH[t] = __builtin_amdgcn_mfma_f32_16x16x32_f16(ah, bh, accH[t], 0, 0, 0);
            accC[t] = __builtin_amdgcn_mfma_f32_16x16x32_f16(ah, bl, accC[t], 0, 0, 0);
            accC[t] = __builtin_amdgcn_mfma_f32_16x16x32_f16(al, bh, accC[t], 0, 0, 0);
        }

        if ((j & 7) == 7) {     // fp64 fold every 256 K
#pragma unroll
            for (int t = 0; t < 4; t++)
#pragma unroll
                for (int r = 0; r < 4; r++) {
                    accD[t][r] += (double)accH[t][r] + (double)accC[t][r] * (1.0 / 4096.0);
                    accH[t][r] = 0.0f;
                    accC[t][r] = 0.0f;
                }
        }

        MEMFENCE;
        __builtin_amdgcn_s_barrier();   // all reads of buf done before restaging it

        cur = (cur == 2) ? 0 : cur + 1;
        nxt = (nxt == 2) ? 0 : nxt + 1;
    }

    // drain tail staging before aliasing LDS for the fp64 reduce
    asm volatile("s_waitcnt vmcnt(0)" ::: "memory");
    __syncthreads();

    double* red = (double*)smem;        // 2*64*17 doubles = 17KB, aliases buf0
    if (kh == 1) {
#pragma unroll
        for (int t = 0; t < 4; t++)
#pragma unroll
            for (int r = 0; r < 4; r++)
                red[(tg * 64 + lane) * 17 + t * 4 + r] = accD[t][r];
    }
    __syncthreads();
    if (kh == 1) return;

#pragma unroll
    for (int t = 0; t < 4; t++)
#pragma unroll
        for (int r = 0; r < 4; r++)
            accD[t][r] += red[(tg * 64 + lane) * 17 + t * 4 + r];

    // ---- epilogue: per token row, softmax + top2 + combine + hist ----
    const int rowg = lane >> 4;
#pragma unroll
    for (int r = 0; r < 4; r++) {
        float lv[4];
#pragma unroll
        for (int t = 0; t < 4; t++) lv[t] = (float)(accD[t][r] * (1.0 / 64.0));

        float m = fmaxf(fmaxf(lv[0], lv[1]), fmaxf(lv[2], lv[3]));
#pragma unroll
        for (int d = 1; d < 16; d <<= 1) m = fmaxf(m, __shfl_xor(m, d));

        // local top2 over this lane's 4 experts (ascending index)
        float l1 = -INFINITY, l2 = -INFINITY;
        int i1 = 0, i2 = 0;
#pragma unroll
        for (int t = 0; t < 4; t++) {
            const float l = lv[t];
            const int e = t * 16 + col;
            if (l > l1)      { l2 = l1; i2 = i1; l1 = l; i1 = e; }
            else if (l > l2) { l2 = l;  i2 = e; }
        }
        // cross-lane top2 merge within the 16-lane row group (lowest-idx ties)
#pragma unroll
        for (int d = 1; d < 16; d <<= 1) {
            const float ol1 = __shfl_xor(l1, d), ol2 = __shfl_xor(l2, d);
            const int   oi1 = __shfl_xor(i1, d), oi2 = __shfl_xor(i2, d);
            if (ol1 > l1 || (ol1 == l1 && oi1 < i1)) {
                if (l1 > ol2 || (l1 == ol2 && i1 < oi2)) { l2 = l1;  i2 = i1;  }
                else                                     { l2 = ol2; i2 = oi2; }
                l1 = ol1; i1 = oi1;
            } else if (ol1 > l2 || (ol1 == l2 && oi1 < i2)) {
                l2 = ol1; i2 = oi1;
            }
        }

        float ex[4];
        double sd = 0.0;
#pragma unroll
        for (int t = 0; t < 4; t++) { ex[t] = expf(lv[t] - m); sd += (double)ex[t]; }
#pragma unroll
        for (int d = 1; d < 16; d <<= 1) sd += __shfl_xor(sd, d);
        const float inv = (float)(1.0 / sd);

        const int tok = t0 + tg * 16 + rowg * 4 + r;
        float* pp = out + OFF_PROBS + (size_t)tok * NUM_EXPERTS + col;
#pragma unroll
        for (int t = 0; t < 4; t++) pp[t * 16] = ex[t] * inv;

        if (col == 0) {
            const float p1 = expf(l1 - m) * inv;
            const float p2 = expf(l2 - m) * inv;
            const float e2 = expf(p2 - p1);
            const float rr = 1.0f / (1.0f + e2);
            out[OFF_COMBINE + 2 * tok]     = rr;
            out[OFF_COMBINE + 2 * tok + 1] = e2 * rr;
            flat_idx[2 * tok]     = i1;
            flat_idx[2 * tok + 1] = i2;
            atomicAdd(&segHist[(tok >> 6) * NUM_EXPERTS + i1], 1);
            atomicAdd(&segHist[(tok >> 6) * NUM_EXPERTS + i2], 1);
        }
    }
}

// ---------------------------------------------------------------------------
// Kernel 3: scan segment hists. 2-level: 4 groups of 64 segments (chain len 64)
// + wave-shuffle prefix for expert bases. 1 block x 256 threads. (unchanged)
// ---------------------------------------------------------------------------
__global__ __launch_bounds__(256) void scan_kernel(
    const int* __restrict__ segHist, int* __restrict__ segOff,
    float* __restrict__ out)
{
    __shared__ int h[NSEG * NUM_EXPERTS];   // 64 KB
    __shared__ int gtot[4 * NUM_EXPERTS];
    __shared__ int base[NUM_EXPERTS];
    const int tid = threadIdx.x;
    for (int i = tid; i < NSEG * NUM_EXPERTS / 4; i += 256)
        *(int4*)(h + i * 4) = *(const int4*)(segHist + i * 4);
    __syncthreads();

    const int e = tid & 63;
    const int g = tid >> 6;                 // 0..3
    int run = 0;
    for (int s = g * 64; s < g * 64 + 64; s++) {
        const int idx = s * NUM_EXPERTS + e;
        const int v = h[idx];
        h[idx] = run;
        run += v;
    }
    gtot[g * NUM_EXPERTS + e] = run;
    __syncthreads();

    if (tid < NUM_EXPERTS) {
        int b = 0;
#pragma unroll
        for (int gg = 0; gg < 4; gg++) {
            const int t = gtot[gg * NUM_EXPERTS + tid];
            gtot[gg * NUM_EXPERTS + tid] = b;
            b += t;
        }
        out[OFF_SPLITS + tid] = (float)b;
        int xs = b;                          // inclusive wave scan over experts
#pragma unroll
        for (int off = 1; off < 64; off <<= 1) {
            const int v = __shfl_up(xs, off);
            if (tid >= off) xs += v;
        }
        base[tid] = xs - b;                  // exclusive
    }
    __syncthreads();

    const int myoff = gtot[g * NUM_EXPERTS + e] + base[e];
    for (int s = g * 64; s < g * 64 + 64; s++) {
        const int idx = s * NUM_EXPERTS + e;
        segOff[idx] = h[idx] + myoff;
    }
}

// ---------------------------------------------------------------------------
// Kernel 4: stable scatter via ballot-match ranks (unchanged, verified)
// ---------------------------------------------------------------------------
__global__ __launch_bounds__(256) void scatter_kernel(
    const int* __restrict__ flat_idx, const int* __restrict__ segOff,
    float* __restrict__ out)
{
    __shared__ int cnt[2 * NUM_EXPERTS];
    const int tid = threadIdx.x;
    const int i = blockIdx.x * 256 + tid;
    const int e = flat_idx[i];
    const int lane = tid & 63;
    const int wv = tid >> 6;
    const int segslot = wv >> 1;
    const int seg = i >> 7;

    if (tid < 2 * NUM_EXPERTS) cnt[tid] = 0;
    __syncthreads();

    unsigned long long match = ~0ull;
#pragma unroll
    for (int b = 0; b < 6; b++) {
        const unsigned long long m = __ballot((e >> b) & 1);
        match &= ((e >> b) & 1) ? m : ~m;
    }
    const int rank = __popcll(match & ((1ull << lane) - 1ull));

    int pos = 0;
    if ((wv & 1) == 0) {
        pos = segOff[seg * NUM_EXPERTS + e] + rank;
        if (lane == __builtin_ctzll(match))
            cnt[segslot * NUM_EXPERTS + e] = __popcll(match);
    }
    __syncthreads();
    if ((wv & 1) == 1)
        pos = segOff[seg * NUM_EXPERTS + e] + cnt[segslot * NUM_EXPERTS + e] + rank;

    out[OFF_TOKEN_ORDER + pos] = (float)(i >> 1);
    out[OFF_REVERSED + i]      = (float)pos;
}

// ---------------------------------------------------------------------------
extern "C" void kernel_launch(void* const* d_in, const int* in_sizes, int n_in,
                              void* d_out, int out_size, void* d_ws, size_t ws_size,
                              hipStream_t stream) {
    const float* x = (const float*)d_in[0];   // [16384, 2048] fp32
    const float* w = (const float*)d_in[1];   // [64, 2048] fp32
    float* out = (float*)d_out;

    int* flat_idx = (int*)d_ws;                          // NK ints
    int* segHist  = flat_idx + NK;                       // 256*64
    int* segOff   = segHist + NSEG * NUM_EXPERTS;        // 256*64
    half8* WH = (half8*)(segOff + NSEG * NUM_EXPERTS);   // 16384 frags (256 KB)
    half8* WL = WH + NFRAG;                              // 256 KB

    preconvert<<<64, 256, 0, stream>>>(w, WH, WL, segHist);
    gate_fused<<<512, 256, 0, stream>>>(x, WH, WL, out, flat_idx, segHist);
    scan_kernel<<<1, 256, 0, stream>>>(segHist, segOff, out);
    scatter_kernel<<<NK / 256, 256, 0, stream>>>(flat_idx, segOff, out);
}